// Round 1
// baseline (59.137 us; speedup 1.0000x reference)
//
#include <hip/hip_runtime.h>
#include <hip/hip_bf16.h>

// FTRL wide-model forward. Reference:
//   z_g = z[idx]; n_g = n[idx]
//   w = (|z_g| <= L1) ? 0 : (sign(z_g)*L1 - z_g) / ((BETA + sqrt(n_g))/ALPHA + L2)
//   out = sigmoid(clip(sum_f w, -35, 35) + fc_b)
// Hyperparams baked in: ALPHA=0.1, BETA=1.0, L1=1.0, L2=1.0
//
// B=16384, F=100, D=2^26. One 64-lane wave per sample.

#ifndef FTRL_B
#define FTRL_B 16384
#endif
#ifndef FTRL_F
#define FTRL_F 100
#endif

__global__ __launch_bounds__(256) void ftrl_wide_kernel(
    const int* __restrict__ idx,     // (B, F)
    const float* __restrict__ z,     // (D,)
    const float* __restrict__ n,     // (D,)
    const float* __restrict__ fc_b,  // (1,)
    float* __restrict__ out,         // (B,)
    int B, int F) {
  const int gtid = blockIdx.x * blockDim.x + threadIdx.x;
  const int wave = gtid >> 6;   // one wave per sample
  const int lane = threadIdx.x & 63;
  if (wave >= B) return;

  const float ALPHA = 0.1f, BETA = 1.0f, L1 = 1.0f, L2 = 1.0f;

  const int* __restrict__ row = idx + (long long)wave * F;

  float acc = 0.0f;
  // F=100 -> lanes 0..35 handle 2 features, lanes 36..63 handle 1.
  for (int f = lane; f < F; f += 64) {
    const int j = row[f];
    const float zg = z[j];
    // sign = (zg < 0) ? -1 : +1 ; w nonzero iff sign*zg > L1 i.e. |zg| > L1
    if (fabsf(zg) > L1) {
      const float ng = n[j];  // conditional gather: skip ~38% of n lines
      const float sgn = (zg < 0.0f) ? -1.0f : 1.0f;
      const float w = (sgn * L1 - zg) / ((BETA + sqrtf(ng)) / ALPHA + L2);
      acc += w;
    }
  }

  // 64-lane butterfly reduction
  #pragma unroll
  for (int off = 32; off > 0; off >>= 1) acc += __shfl_down(acc, off);

  if (lane == 0) {
    float wz = fminf(fmaxf(acc, -35.0f), 35.0f);
    const float x = wz + fc_b[0];        // deep_z is just the bias
    out[wave] = 1.0f / (1.0f + __expf(-x));
  }
}

extern "C" void kernel_launch(void* const* d_in, const int* in_sizes, int n_in,
                              void* d_out, int out_size, void* d_ws, size_t ws_size,
                              hipStream_t stream) {
  // setup_inputs order: X_w_indices (B*F int32), z (D f32), n (D f32),
  //                     fc_w (1 f32, unused: multiplies zeros), fc_b (1 f32)
  const int* idx    = (const int*)d_in[0];
  const float* z    = (const float*)d_in[1];
  const float* n    = (const float*)d_in[2];
  const float* fc_b = (const float*)d_in[4];
  float* out        = (float*)d_out;

  const int B = out_size;               // 16384
  const int F = in_sizes[0] / B;        // 100

  const int threads = 256;              // 4 waves/block -> 4 samples/block
  const int blocks = (B * 64 + threads - 1) / threads;
  ftrl_wide_kernel<<<blocks, threads, 0, stream>>>(idx, z, n, fc_b, out, B, F);
}

// Round 2
// 56.467 us; speedup vs baseline: 1.0473x; 1.0473x over previous
//
#include <hip/hip_runtime.h>
#include <hip/hip_bf16.h>

// FTRL wide-model forward. Reference:
//   z_g = z[idx]; n_g = n[idx]
//   w = (|z_g| <= L1) ? 0 : (sign(z_g)*L1 - z_g) / ((BETA + sqrt(n_g))/ALPHA + L2)
//   out = sigmoid(clip(sum_f w, -35, 35) + fc_b)
// Hyperparams baked in: ALPHA=0.1, BETA=1.0, L1=1.0, L2=1.0
//   -> denominator = 10*sqrt(n) + 11
//
// B=16384, F=100, D=2^26. One 64-lane wave per sample.
// Restructured for memory-level parallelism: issue BOTH idx loads, then BOTH
// z gathers, then BOTH (conditional) n gathers before any dependent use —
// 3 dependent latency stages instead of ~6 in the rolled loop.

__global__ __launch_bounds__(256) void ftrl_wide_kernel(
    const int* __restrict__ idx,     // (B, F)
    const float* __restrict__ z,     // (D,)
    const float* __restrict__ n,     // (D,)
    const float* __restrict__ fc_b,  // (1,)
    float* __restrict__ out,         // (B,)
    int B, int F) {
  const int gtid = blockIdx.x * blockDim.x + threadIdx.x;
  const int wave = gtid >> 6;   // one wave per sample
  const int lane = threadIdx.x & 63;
  if (wave >= B) return;

  const int* __restrict__ row = idx + (long long)wave * F;
  const bool has2 = (lane + 64) < F;   // F=100: lanes 0..35 take a 2nd feature

  // Stage 1: both index loads in flight together (coalesced).
  const int j0 = row[lane];
  int j1 = 0;
  if (has2) j1 = row[lane + 64];

  // Stage 2: both z gathers in flight together. Non-temporal: zero reuse.
  const float zg0 = __builtin_nontemporal_load(z + j0);
  float zg1 = 0.0f;
  if (has2) zg1 = __builtin_nontemporal_load(z + j1);

  // Stage 3: both conditional n gathers in flight together.
  const bool need0 = fabsf(zg0) > 1.0f;           // w != 0 iff |z| > L1
  const bool need1 = has2 && (fabsf(zg1) > 1.0f);
  float ng0 = 0.0f, ng1 = 0.0f;
  if (need0) ng0 = __builtin_nontemporal_load(n + j0);
  if (need1) ng1 = __builtin_nontemporal_load(n + j1);

  // Arithmetic (uses wait on the loads above).
  float acc = 0.0f;
  if (need0) {
    const float sgn = (zg0 < 0.0f) ? -1.0f : 1.0f;
    acc += (sgn - zg0) / fmaf(10.0f, sqrtf(ng0), 11.0f);
  }
  if (need1) {
    const float sgn = (zg1 < 0.0f) ? -1.0f : 1.0f;
    acc += (sgn - zg1) / fmaf(10.0f, sqrtf(ng1), 11.0f);
  }

  // 64-lane butterfly reduction
  #pragma unroll
  for (int off = 32; off > 0; off >>= 1) acc += __shfl_down(acc, off);

  if (lane == 0) {
    const float wz = fminf(fmaxf(acc, -35.0f), 35.0f);
    const float x = wz + fc_b[0];        // deep_z is just the bias
    out[wave] = 1.0f / (1.0f + __expf(-x));
  }
}

extern "C" void kernel_launch(void* const* d_in, const int* in_sizes, int n_in,
                              void* d_out, int out_size, void* d_ws, size_t ws_size,
                              hipStream_t stream) {
  // setup_inputs order: X_w_indices (B*F int32), z (D f32), n (D f32),
  //                     fc_w (1 f32, unused: multiplies zeros), fc_b (1 f32)
  const int* idx    = (const int*)d_in[0];
  const float* z    = (const float*)d_in[1];
  const float* n    = (const float*)d_in[2];
  const float* fc_b = (const float*)d_in[4];
  float* out        = (float*)d_out;

  const int B = out_size;               // 16384
  const int F = in_sizes[0] / B;        // 100

  const int threads = 256;              // 4 waves/block -> 4 samples/block
  const int blocks = (B * 64 + threads - 1) / threads;
  ftrl_wide_kernel<<<blocks, threads, 0, stream>>>(idx, z, n, fc_b, out, B, F);
}